// Round 10
// baseline (227.116 us; speedup 1.0000x reference)
//
#include <hip/hip_runtime.h>
#include <hip/hip_bf16.h>
#include <cstdint>
#include <cstddef>

#define NB   32
#define CIN  128
#define HWP  3136          // 56*56
#define KOC  256
#define NRS  9
#define PROW 3364          // 58*58 padded rows per (n,ck)
#define GUARD 256          // staging over-read guard rows at end of xt
#define BEL  8192          // elems per B window buffer = 256 rows * 32 (16 KB)

typedef __attribute__((ext_vector_type(8))) short  short8;
typedef __attribute__((ext_vector_type(4))) short  short4v;
typedef __attribute__((ext_vector_type(4))) float  float4v;

__device__ __forceinline__ unsigned short f2bf(float f) {
    union { float f; unsigned int u; } v; v.f = f;
    unsigned int u = v.u;
    u = u + 0x7fffu + ((u >> 16) & 1u);   // RNE
    return (unsigned short)(u >> 16);
}

// ---------------------------------------------------------------------------
// Fused prep kernel, three independent jobs (disjoint outputs, no ordering):
//   blocks [0, 1152):      W (OIHW fp32) -> wt2, layout
//                          [ot][g][s][wm][i][quad][lr][e]   (g = ck*3+r)
//                          (strides: ot 147456, g 12288, s 4096, wm 2048,
//                           i 512, quad 128, lr 8, e 1)
//                          -> for a fixed (ot,wm), tap T = g*3+s lives at
//                          offset T*4096: the gemm kernel's A walk is ONE
//                          running pointer += 4096 across all 36 taps.
//   blocks [1152, 2816):   x NCHW fp32 -> xt[n][ck][p'][32c] bf16 halo layout
//   blocks [2816, 2930):   zero the 228 guard rows per (n,ck) slab
// ---------------------------------------------------------------------------
__global__ __launch_bounds__(256) void prep_kernel(const float* __restrict__ W,
                                                   unsigned short* __restrict__ wt2,
                                                   const float* __restrict__ x,
                                                   unsigned short* __restrict__ xt) {
    __shared__ unsigned short lds[32 * 260];
    int blk = blockIdx.x;
    int t   = threadIdx.x;

    if (blk < 1152) {
        // ---- wt2 part ----
        int idx  = blk * 256 + t;
        int e    = idx & 7;
        int lr   = (idx >> 3) & 15;
        int quad = (idx >> 7) & 3;
        int i    = (idx >> 9) & 3;
        int wm   = (idx >> 11) & 1;
        int q    = idx >> 12;          // 0..71: (ot*12 + g)*3 + s
        int s    = q % 3;
        int gg   = q / 3;              // ot*12 + g
        int g    = gg % 12;
        int ot   = gg / 12;
        int ck   = g / 3;
        int r    = g % 3;
        int oc = ot * 128 + wm * 64 + i * 16 + lr;
        int c  = ck * 32 + quad * 8 + e;
        wt2[idx] = f2bf(W[((size_t)oc * CIN + c) * NRS + r * 3 + s]);
        return;
    }

    if (blk >= 2816) {
        // ---- guard-zero part: 128 slabs x 228 guard rows, 64 B each ----
        int g = (blk - 2816) * 256 + t;            // 0 .. 29183 (exact)
        int slab = g / 228;
        int gi   = g - slab * 228;
        int row;
        if (gi < 59)       row = gi;                               // top halo
        else if (gi < 169) { int k = gi - 59;                      // seam gaps
                             row = 115 + 58 * (k >> 1) + (k & 1); }
        else               row = 3305 + (gi - 169);                // bottom halo
        unsigned short* gr = xt + (size_t)slab * (PROW * 32) + (size_t)row * 32;
        short8 z = (short8)0;
        *(short8*)(gr +  0) = z;
        *(short8*)(gr +  8) = z;
        *(short8*)(gr + 16) = z;
        *(short8*)(gr + 24) = z;
        return;
    }

    // ---- xpose part (interior rows) ----
    int b    = blk - 1152;
    int tile = b % 13;
    int ck   = (b / 13) & 3;
    int n    = b / 52;
    int hw0  = tile * 256;
    int wv   = t >> 6;
    int lane = t & 63;

    const float* src = x + ((size_t)(n * CIN + ck * 32)) * HWP;
    #pragma unroll
    for (int pass = 0; pass < 8; ++pass) {
        int c  = pass * 4 + wv;
        int hw = hw0 + lane * 4;
        if (hw < HWP) {
            float4v v = *(const float4v*)(src + (size_t)c * HWP + hw);
            short4v s4;
            #pragma unroll
            for (int k = 0; k < 4; ++k) s4[k] = (short)f2bf(v[k]);
            *(short4v*)(&lds[c * 260 + lane * 4]) = s4;
        }
    }
    __syncthreads();

    int sub = t & 3;
    int hwl = t >> 2;
    unsigned short* dst = xt + ((size_t)(n * 4 + ck)) * PROW * 32;
    #pragma unroll
    for (int pass = 0; pass < 4; ++pass) {
        int hl = pass * 64 + hwl;
        int hw = hw0 + hl;
        if (hw < HWP) {
            short8 v;
            #pragma unroll
            for (int j = 0; j < 8; ++j)
                v[j] = (short)lds[(sub * 8 + j) * 260 + hl];
            int pr = hw + 59 + 2 * (hw / 56);
            *(short8*)(dst + (size_t)pr * 32 + sub * 8) = v;
        }
    }
}

// ---------------------------------------------------------------------------
// Stage one 256-row halo window (16 KB) into LDS via async global_load_lds.
// XOR swizzle: LDS slot (r,q) holds global 16B-chunk (r, q ^ ((r>>1)&3)).
// 4 waves x 4 instructions cover all 1024 slots.
// ---------------------------------------------------------------------------
__device__ __forceinline__ void stage_B(const unsigned short* gwin,
                                        unsigned short* lbase,
                                        int wv, int lane) {
    #pragma unroll
    for (int it = 0; it < 4; ++it) {
        int blk = it * 4 + wv;             // wave-chunk 0..15 (wave-uniform)
        int s   = blk * 64 + lane;         // slot 0..1023
        int r   = s >> 2;
        int q   = s & 3;
        int qs  = q ^ ((r >> 1) & 3);
        __builtin_amdgcn_global_load_lds(
            (const __attribute__((address_space(1))) void*)(gwin + r * 32 + qs * 8),
            (__attribute__((address_space(3))) void*)(lbase + (size_t)blk * 512), 16, 0, 0);
    }
}

__device__ __forceinline__ short8 ldb(const char* lb, int r, int quad) {
    int q = quad ^ ((r >> 1) & 3);
    return *(const short8*)(lb + r * 64 + q * 16);
}

// ---------------------------------------------------------------------------
// Implicit GEMM: 128 oc x 128 px per block, 4 waves (2 oc x 2 px), wave tile
// 64x64 via 4x4 mfma_f32_16x16x32_bf16.
//
// Config ledger: {64x64, A+B dbuf in LDS} = 80 KB -> only 8 waves/CU,
// latency-bound (r5: 87.8us). {64x32, dbuf} = 16 waves/CU but 1.5x LDS
// traffic -> port-bound (r8: 71us). {64x64, single-buf} = staging on the
// critical path (r9: 85us). The feasible point with 64x64 traffic AND
// r8-class TLP: A NEVER in LDS.
//
// A register pipeline: af_cur/af_nxt (32 VGPR). wt2's [ot][g][s] layout
// makes all 36 taps one linear walk (agp += 4096/tap). Each tap issues the
// NEXT tap's 4 global b128 loads (L2-hot wt2, 576 KB/XCD working set),
// ~900 wall-cyc before use at 3 waves/SIMD -> covers L2 latency (200-600).
// r7's version of this spilled from TRANSIENT pressure (af[12]=48 regs +
// wrap arithmetic); this one: af 32 + b 8 + rb 4 + acc 64 AGPR + addr ~25
// ~= 133 <= 168 cap (__launch_bounds__(256,3)), margin ~35.
// LDS = B halo dbuf only (2x16 KB): per-CU LDS traffic 3.6 MB (~25% port).
// 3 blocks/CU = 12 waves/CU. Barriers: 4/block (ck boundaries only).
// B staged late (during r==2) so A-tap vmcnt waits never queue behind the
// 16 KB DMA; ck-end barrier drains it, covered by the other 2 blocks.
// No-spill signature: WRITE_SIZE == 100352 KB exactly.
// ---------------------------------------------------------------------------
__global__ __launch_bounds__(256, 3) void gemm_kernel(const unsigned short* __restrict__ xt,
                                                      const unsigned short* __restrict__ wt2,
                                                      const float* __restrict__ bias,
                                                      float* __restrict__ out) {
    __shared__ unsigned short lds[2 * BEL];   // 32 KB: B0@0 B1@8192

    int bx0 = blockIdx.x;                 // 25 pt x 32 n x 2 ot = 1600
    int bx  = (bx0 & 7) * 200 + (bx0 >> 3);   // XCD chunk swizzle (bijective)
    int ot  = bx & 1;
    int n   = (bx >> 1) & 31;
    int pt  = bx >> 6;
    int p0  = pt * 128;

    int t    = threadIdx.x;
    int wv   = t >> 6;                    // 0..3
    int lane = t & 63;
    int lr   = lane & 15;
    int quad = lane >> 4;
    int wm   = wv >> 1;                   // oc half (64 oc)
    int wn   = wv & 1;                    // px half (64 px)

    int prbase = p0 + 2 * (p0 / 56);      // = pr(p0) - 59, >= 0

    // per-j window row of the center tap (shift 0); clamped for tail tile
    int rb[4];
    #pragma unroll
    for (int j = 0; j < 4; ++j) {
        int hw  = p0 + wn * 64 + j * 16 + lr;
        int hwc = hw < HWP ? hw : (HWP - 1);
        rb[j] = hwc + 59 + 2 * (hwc / 56) - prbase;   // in [59, 193)
    }

    const unsigned short* xb  = xt + (size_t)n * 4 * PROW * 32;
    // A running pointer, linear across all 36 taps (+4096/tap)
    const unsigned short* agp = wt2 + ot * 147456 + wm * 2048 + lane * 8;

    float4v acc[4][4];
    #pragma unroll
    for (int i = 0; i < 4; ++i)
        #pragma unroll
        for (int j = 0; j < 4; ++j)
            acc[i][j] = (float4v){0.f, 0.f, 0.f, 0.f};

    short8 af_cur[4], af_nxt[4];

    // prologue: stage B(ck=0) -> B0; load tap 0 fragments
    stage_B(xb + (size_t)prbase * 32, lds, wv, lane);
    #pragma unroll
    for (int i = 0; i < 4; ++i)
        af_cur[i] = *(const short8*)(agp + i * 512);
    __syncthreads();

    for (int ck = 0; ck < 4; ++ck) {
        const char* lbB = (const char*)(lds + (ck & 1) * BEL);
        #pragma unroll
        for (int r = 0; r < 3; ++r) {
            int sh0 = (r - 1) * 58;
            #pragma unroll
            for (int s = 0; s < 3; ++s) {
                // prefetch next tap's A into the spare slot (last tap of the
                // kernel prefetches 4 KB past wt2 -> lands in xt, never used)
                #pragma unroll
                for (int i = 0; i < 4; ++i)
                    af_nxt[i] = *(const short8*)(agp + 4096 + i * 512);
                // stage-late: next ck's B window, once, during the r==2 row
                if (r == 2 && s == 0 && ck < 3)
                    stage_B(xb + (size_t)(ck + 1) * (PROW * 32) + (size_t)prbase * 32,
                            lds + ((ck + 1) & 1) * BEL, wv, lane);

                int shift = sh0 + s - 1;
                short8 bcur = ldb(lbB, rb[0] + shift, quad);
                __builtin_amdgcn_s_setprio(1);
                #pragma unroll
                for (int j = 0; j < 4; ++j) {
                    short8 bnext;
                    if (j < 3) bnext = ldb(lbB, rb[j + 1] + shift, quad);
                    #pragma unroll
                    for (int i = 0; i < 4; ++i)
                        acc[i][j] = __builtin_amdgcn_mfma_f32_16x16x32_bf16(
                            af_cur[i], bcur, acc[i][j], 0, 0, 0);
                    if (j < 3) bcur = bnext;
                }
                __builtin_amdgcn_s_setprio(0);
                #pragma unroll
                for (int i = 0; i < 4; ++i) af_cur[i] = af_nxt[i];
                agp += 4096;
            }
        }
        __syncthreads();   // drains this wave's B DMA; all waves done with B[ck&1]
    }

    // epilogue: D row = oc (quad*4+reg), col = pixel (lane&15)
    float* orow = out + (size_t)n * KOC * HWP;
    #pragma unroll
    for (int i = 0; i < 4; ++i) {
        #pragma unroll
        for (int rr = 0; rr < 4; ++rr) {
            int oc = ot * 128 + wm * 64 + i * 16 + quad * 4 + rr;
            float bi = bias[oc];
            #pragma unroll
            for (int j = 0; j < 4; ++j) {
                int hw = p0 + wn * 64 + j * 16 + lr;
                if (hw < HWP)
                    orow[(size_t)oc * HWP + hw] = acc[i][j][rr] + bi;
            }
        }
    }
}

// ---------------------------------------------------------------------------
// Safety fallback if ws is too small: naive direct conv (exact fp32).
// ---------------------------------------------------------------------------
__global__ void naive_kernel(const float* __restrict__ x, const float* __restrict__ W,
                             const float* __restrict__ b, float* __restrict__ out) {
    size_t idx = (size_t)blockIdx.x * 256 + threadIdx.x;
    if (idx >= (size_t)NB * KOC * HWP) return;
    int w0 = (int)(idx % 56);
    int h0 = (int)((idx / 56) % 56);
    int k  = (int)((idx / HWP) % KOC);
    int n  = (int)(idx / ((size_t)HWP * KOC));
    float acc = b[k];
    for (int c = 0; c < CIN; ++c) {
        const float* xr = x + ((size_t)n * CIN + c) * HWP;
        const float* wr = W + ((size_t)k * CIN + c) * NRS;
        for (int r = 0; r < 3; ++r) {
            int h = h0 + r - 1;
            if ((unsigned)h >= 56u) continue;
            for (int s = 0; s < 3; ++s) {
                int w = w0 + s - 1;
                if ((unsigned)w >= 56u) continue;
                acc += xr[h * 56 + w] * wr[r * 3 + s];
            }
        }
    }
    out[idx] = acc;
}

extern "C" void kernel_launch(void* const* d_in, const int* in_sizes, int n_in,
                              void* d_out, int out_size, void* d_ws, size_t ws_size,
                              hipStream_t stream) {
    const float* x  = (const float*)d_in[0];
    const float* W  = (const float*)d_in[1];
    const float* b  = (const float*)d_in[2];
    float* out = (float*)d_out;

    const size_t wt_elems = (size_t)NRS * 4 * 2 * 2 * 4 * 4 * 16 * 8;   // 294912
    const size_t xt_elems = (size_t)NB * 4 * PROW * 32 + (size_t)GUARD * 32;
    const size_t need = (wt_elems + xt_elems) * sizeof(unsigned short); // ~28.2 MB

    if (ws_size < need) {
        size_t total = (size_t)NB * KOC * HWP;
        naive_kernel<<<(unsigned)((total + 255) / 256), 256, 0, stream>>>(x, W, b, out);
        return;
    }

    unsigned short* wt2 = (unsigned short*)d_ws;
    unsigned short* xt  = wt2 + wt_elems;        // 16B-aligned

    // prep zeroes only the 228 guard rows per slab (no full-buffer memset)
    prep_kernel<<<1152 + NB * 4 * 13 + 114, 256, 0, stream>>>(W, wt2, x, xt);
    gemm_kernel<<<1600, 256, 0, stream>>>(xt, wt2, b, out);
}

// Round 11
// 202.662 us; speedup vs baseline: 1.1207x; 1.1207x over previous
//
#include <hip/hip_runtime.h>
#include <hip/hip_bf16.h>
#include <cstdint>
#include <cstddef>

#define NB   32
#define CIN  128
#define HWP  3136          // 56*56
#define KOC  256
#define NRS  9
#define PROW 3364          // 58*58 padded rows per (n,ck)
#define GUARD 256          // staging over-read guard rows at end of xt
#define TEL  4096          // elems per A tap slab (8 KB)
#define BEL  8192          // elems per B window buffer = 256 rows * 32 (16 KB)

typedef __attribute__((ext_vector_type(8))) short  short8;
typedef __attribute__((ext_vector_type(4))) short  short4v;
typedef __attribute__((ext_vector_type(4))) float  float4v;

#define VM_WAIT(n) asm volatile("s_waitcnt vmcnt(" #n ")" ::: "memory")

__device__ __forceinline__ unsigned short f2bf(float f) {
    union { float f; unsigned int u; } v; v.f = f;
    unsigned int u = v.u;
    u = u + 0x7fffu + ((u >> 16) & 1u);   // RNE
    return (unsigned short)(u >> 16);
}

// ---------------------------------------------------------------------------
// Fused prep kernel, three independent jobs (disjoint outputs, no ordering):
//   blocks [0, 1152):      W (OIHW fp32) -> wt2, layout
//                          [ot][tap][wm][i][quad][lr][e]   (tap = (ck*3+r)*3+s)
//                          (strides: ot 147456, tap 4096, wm 2048, i 512,
//                           quad 128, lr 8, e 1)
//                          -> each 8 KB tap slab stages LINEARLY into LDS.
//   blocks [1152, 2816):   x NCHW fp32 -> xt[n][ck][p'][32c] bf16 halo layout
//   blocks [2816, 2930):   zero the 228 guard rows per (n,ck) slab
// ---------------------------------------------------------------------------
__global__ __launch_bounds__(256) void prep_kernel(const float* __restrict__ W,
                                                   unsigned short* __restrict__ wt2,
                                                   const float* __restrict__ x,
                                                   unsigned short* __restrict__ xt) {
    __shared__ unsigned short lds[32 * 260];
    int blk = blockIdx.x;
    int t   = threadIdx.x;

    if (blk < 1152) {
        // ---- wt2 part ----
        int idx  = blk * 256 + t;
        int e    = idx & 7;
        int lr   = (idx >> 3) & 15;
        int quad = (idx >> 7) & 3;
        int i    = (idx >> 9) & 3;
        int wm   = (idx >> 11) & 1;
        int q    = idx >> 12;          // 0..71: ot*36 + tap
        int tap  = q % 36;
        int ot   = q / 36;
        int s    = tap % 3;
        int r    = (tap / 3) % 3;
        int ck   = tap / 9;
        int oc = ot * 128 + wm * 64 + i * 16 + lr;
        int c  = ck * 32 + quad * 8 + e;
        wt2[idx] = f2bf(W[((size_t)oc * CIN + c) * NRS + r * 3 + s]);
        return;
    }

    if (blk >= 2816) {
        // ---- guard-zero part: 128 slabs x 228 guard rows, 64 B each ----
        int g = (blk - 2816) * 256 + t;            // 0 .. 29183 (exact)
        int slab = g / 228;
        int gi   = g - slab * 228;
        int row;
        if (gi < 59)       row = gi;                               // top halo
        else if (gi < 169) { int k = gi - 59;                      // seam gaps
                             row = 115 + 58 * (k >> 1) + (k & 1); }
        else               row = 3305 + (gi - 169);                // bottom halo
        unsigned short* gr = xt + (size_t)slab * (PROW * 32) + (size_t)row * 32;
        short8 z = (short8)0;
        *(short8*)(gr +  0) = z;
        *(short8*)(gr +  8) = z;
        *(short8*)(gr + 16) = z;
        *(short8*)(gr + 24) = z;
        return;
    }

    // ---- xpose part (interior rows) ----
    int b    = blk - 1152;
    int tile = b % 13;
    int ck   = (b / 13) & 3;
    int n    = b / 52;
    int hw0  = tile * 256;
    int wv   = t >> 6;
    int lane = t & 63;

    const float* src = x + ((size_t)(n * CIN + ck * 32)) * HWP;
    #pragma unroll
    for (int pass = 0; pass < 8; ++pass) {
        int c  = pass * 4 + wv;
        int hw = hw0 + lane * 4;
        if (hw < HWP) {
            float4v v = *(const float4v*)(src + (size_t)c * HWP + hw);
            short4v s4;
            #pragma unroll
            for (int k = 0; k < 4; ++k) s4[k] = (short)f2bf(v[k]);
            *(short4v*)(&lds[c * 260 + lane * 4]) = s4;
        }
    }
    __syncthreads();

    int sub = t & 3;
    int hwl = t >> 2;
    unsigned short* dst = xt + ((size_t)(n * 4 + ck)) * PROW * 32;
    #pragma unroll
    for (int pass = 0; pass < 4; ++pass) {
        int hl = pass * 64 + hwl;
        int hw = hw0 + hl;
        if (hw < HWP) {
            short8 v;
            #pragma unroll
            for (int j = 0; j < 8; ++j)
                v[j] = (short)lds[(sub * 8 + j) * 260 + hl];
            int pr = hw + 59 + 2 * (hw / 56);
            *(short8*)(dst + (size_t)pr * 32 + sub * 8) = v;
        }
    }
}

// ---------------------------------------------------------------------------
// Stage one 8 KB A tap slab into an LDS ring buffer, linear.
// 4 waves x 2 instructions, 512 x 16B chunks.
// ---------------------------------------------------------------------------
__device__ __forceinline__ void stage_A_tap(const unsigned short* src,
                                            unsigned short* dstbuf,
                                            int wv, int lane) {
    #pragma unroll
    for (int it = 0; it < 2; ++it) {
        int c0 = it * 256 + wv * 64;       // wave-uniform chunk base
        __builtin_amdgcn_global_load_lds(
            (const __attribute__((address_space(1))) void*)(src + (size_t)(c0 + lane) * 8),
            (__attribute__((address_space(3))) void*)(dstbuf + (size_t)c0 * 8), 16, 0, 0);
    }
}

// ---------------------------------------------------------------------------
// Stage one 256-row halo window (16 KB) into LDS via async global_load_lds.
// XOR swizzle: LDS slot (r,q) holds global 16B-chunk (r, q ^ ((r>>1)&3)).
// 4 waves x 4 instructions cover all 1024 slots.
// ---------------------------------------------------------------------------
__device__ __forceinline__ void stage_B(const unsigned short* gwin,
                                        unsigned short* lbase,
                                        int wv, int lane) {
    #pragma unroll
    for (int it = 0; it < 4; ++it) {
        int blk = it * 4 + wv;             // wave-chunk 0..15 (wave-uniform)
        int s   = blk * 64 + lane;         // slot 0..1023
        int r   = s >> 2;
        int q   = s & 3;
        int qs  = q ^ ((r >> 1) & 3);
        __builtin_amdgcn_global_load_lds(
            (const __attribute__((address_space(1))) void*)(gwin + r * 32 + qs * 8),
            (__attribute__((address_space(3))) void*)(lbase + (size_t)blk * 512), 16, 0, 0);
    }
}

__device__ __forceinline__ short8 ldb(const char* lb, int r, int quad) {
    int q = quad ^ ((r >> 1) & 3);
    return *(const short8*)(lb + r * 64 + q * 16);
}

// ---------------------------------------------------------------------------
// Implicit GEMM, pure-LDS inner loop with per-tap pipelined A staging:
// 128 oc x 128 px per block, 4 waves (2 oc x 2 px), wave tile 64x64 via
// 4x4 mfma_f32_16x16x32_bf16.
//
// Ledger: A-in-registers spilled 4/4 attempts (r1/r6/r7/r10: transient
// pressure ~30-40 regs above static estimate) -> both operands from LDS.
// r8 (64x32, A+B dbuf, 16 waves/CU) = 71us, LDS-port-bound (11.1 MB/CU,
// ~76% port busy; recalibrated MFMA pipe cost ~17 cyc/SIMD per mfma from
// r8's MfmaUtil=35.4). 64x64 cuts LDS traffic 1.5x but needs dbuf AND
// >=12 waves/CU -> infeasible with 24 KB A slabs.
//
// Resolution: A staged per TAP (8 KB) into a 4-slot ring, prefetched 3 taps
// (~900 cyc) ahead -> covers L2 latency. B single 16 KB window per ck.
// LDS = 4*8 + 16 = 48 KB -> 3 blocks/CU (reg-gated, __launch_bounds__(256,3)
// = 168-reg cap; r9 measured this exact compute structure at 148 total,
// clean). 12 waves/CU. Per-tap sync is counted-vmcnt + raw s_barrier
// (m201 pattern): vmcnt(4) leaves the 2 future A stages in flight -- the
// pipeline never drains. B re-stage once per ck behind an extra barrier
// (4 exposed ~300cyc waits/block, covered by 2 other resident blocks).
// Floors: LDS 7.37 MB/CU ~ 87k cyc; MFMA ~61k cyc/SIMD.
// No-spill signature: WRITE_SIZE == 100352 KB exactly.
// ---------------------------------------------------------------------------
__global__ __launch_bounds__(256, 3) void gemm_kernel(const unsigned short* __restrict__ xt,
                                                      const unsigned short* __restrict__ wt2,
                                                      const float* __restrict__ bias,
                                                      float* __restrict__ out) {
    __shared__ unsigned short lds[24576];   // 48 KB: A ring 4x4096 @0, B @16384

    int bx0 = blockIdx.x;                 // 25 pt x 32 n x 2 ot = 1600
    int bx  = (bx0 & 7) * 200 + (bx0 >> 3);   // XCD chunk swizzle (bijective)
    int ot  = bx & 1;
    int n   = (bx >> 1) & 31;
    int pt  = bx >> 6;
    int p0  = pt * 128;

    int t    = threadIdx.x;
    int wv   = t >> 6;                    // 0..3
    int lane = t & 63;
    int lr   = lane & 15;
    int quad = lane >> 4;
    int wm   = wv >> 1;                   // oc half (64 oc)
    int wn   = wv & 1;                    // px half (64 px)

    int prbase = p0 + 2 * (p0 / 56);      // = pr(p0) - 59, >= 0

    // per-j window row of the center tap (shift 0); clamped for tail tile
    int rb[4];
    #pragma unroll
    for (int j = 0; j < 4; ++j) {
        int hw  = p0 + wn * 64 + j * 16 + lr;
        int hwc = hw < HWP ? hw : (HWP - 1);
        rb[j] = hwc + 59 + 2 * (hwc / 56) - prbase;   // in [59, 193)
    }

    const unsigned short* xb = xt + (size_t)n * 4 * PROW * 32;
    const unsigned short* wa = wt2 + (size_t)ot * 147456;   // + tap*4096

    float4v acc[4][4];
    #pragma unroll
    for (int i = 0; i < 4; ++i)
        #pragma unroll
        for (int j = 0; j < 4; ++j)
            acc[i][j] = (float4v){0.f, 0.f, 0.f, 0.f};

    // prologue: B(ck=0) + A taps 0,1,2 into ring slots 0,1,2
    stage_B(xb + (size_t)prbase * 32, lds + 16384, wv, lane);
    stage_A_tap(wa,            lds,            wv, lane);
    stage_A_tap(wa + TEL,      lds + TEL,      wv, lane);
    stage_A_tap(wa + 2 * TEL,  lds + 2 * TEL,  wv, lane);

    const char* lbB = (const char*)(lds + 16384);

    #pragma unroll
    for (int ck = 0; ck < 4; ++ck) {
        #pragma unroll
        for (int tc = 0; tc < 9; ++tc) {
            const int tp = ck * 9 + tc;
            // counted wait: leave future A stages in flight (never drain the
            // pipe). At ck-start (B just staged, newest in queue) and at the
            // last tap we must drain to 0.
            if ((tc == 0 && ck > 0) || tp == 35) VM_WAIT(0);
            else if (tp == 34)                   VM_WAIT(2);
            else                                 VM_WAIT(4);
            __builtin_amdgcn_s_barrier();       // all waves' staging visible
            __builtin_amdgcn_sched_barrier(0);  // no ds_read hoists above

            // issue tap tp+3 into ring slot (tp+3)&3 (its previous tenant,
            // tap tp-1, was fully consumed before the barrier above)
            if (tp <= 32)
                stage_A_tap(wa + (size_t)(tp + 3) * TEL,
                            lds + ((tp + 3) & 3) * TEL, wv, lane);

            const unsigned short* A = lds + (tp & 3) * TEL + wm * 2048 + lane * 8;
            const int shift = (tc / 3 - 1) * 58 + (tc % 3) - 1;

            short8 af[4];
            #pragma unroll
            for (int i = 0; i < 4; ++i)
                af[i] = *(const short8*)(A + i * 512);
            short8 bcur = ldb(lbB, rb[0] + shift, quad);
            __builtin_amdgcn_s_setprio(1);
            #pragma unroll
            for (int j = 0; j < 4; ++j) {
                short8 bnext;
                if (j < 3) bnext = ldb(lbB, rb[j + 1] + shift, quad);
                #pragma unroll
                for (int i = 0; i < 4; ++i)
                    acc[i][j] = __builtin_amdgcn_mfma_f32_16x16x32_bf16(
                        af[i], bcur, acc[i][j], 0, 0, 0);
                if (j < 3) bcur = bnext;
            }
            __builtin_amdgcn_s_setprio(0);

            // ck boundary: all waves done reading B[ck] after this barrier;
            // overwrite the single B window with the next ck's halo.
            if (tc == 8 && ck < 3) {
                __builtin_amdgcn_s_barrier();
                stage_B(xb + (size_t)(ck + 1) * (PROW * 32) + (size_t)prbase * 32,
                        lds + 16384, wv, lane);
            }
        }
    }

    // epilogue: D row = oc (quad*4+reg), col = pixel (lane&15)
    float* orow = out + (size_t)n * KOC * HWP;
    #pragma unroll
    for (int i = 0; i < 4; ++i) {
        #pragma unroll
        for (int rr = 0; rr < 4; ++rr) {
            int oc = ot * 128 + wm * 64 + i * 16 + quad * 4 + rr;
            float bi = bias[oc];
            #pragma unroll
            for (int j = 0; j < 4; ++j) {
                int hw = p0 + wn * 64 + j * 16 + lr;
                if (hw < HWP)
                    orow[(size_t)oc * HWP + hw] = acc[i][j][rr] + bi;
            }
        }
    }
}

// ---------------------------------------------------------------------------
// Safety fallback if ws is too small: naive direct conv (exact fp32).
// ---------------------------------------------------------------------------
__global__ void naive_kernel(const float* __restrict__ x, const float* __restrict__ W,
                             const float* __restrict__ b, float* __restrict__ out) {
    size_t idx = (size_t)blockIdx.x * 256 + threadIdx.x;
    if (idx >= (size_t)NB * KOC * HWP) return;
    int w0 = (int)(idx % 56);
    int h0 = (int)((idx / 56) % 56);
    int k  = (int)((idx / HWP) % KOC);
    int n  = (int)(idx / ((size_t)HWP * KOC));
    float acc = b[k];
    for (int c = 0; c < CIN; ++c) {
        const float* xr = x + ((size_t)n * CIN + c) * HWP;
        const float* wr = W + ((size_t)k * CIN + c) * NRS;
        for (int r = 0; r < 3; ++r) {
            int h = h0 + r - 1;
            if ((unsigned)h >= 56u) continue;
            for (int s = 0; s < 3; ++s) {
                int w = w0 + s - 1;
                if ((unsigned)w >= 56u) continue;
                acc += xr[h * 56 + w] * wr[r * 3 + s];
            }
        }
    }
    out[idx] = acc;
}

extern "C" void kernel_launch(void* const* d_in, const int* in_sizes, int n_in,
                              void* d_out, int out_size, void* d_ws, size_t ws_size,
                              hipStream_t stream) {
    const float* x  = (const float*)d_in[0];
    const float* W  = (const float*)d_in[1];
    const float* b  = (const float*)d_in[2];
    float* out = (float*)d_out;

    const size_t wt_elems = (size_t)NRS * 4 * 2 * 2 * 4 * 4 * 16 * 8;   // 294912
    const size_t xt_elems = (size_t)NB * 4 * PROW * 32 + (size_t)GUARD * 32;
    const size_t need = (wt_elems + xt_elems) * sizeof(unsigned short); // ~28.2 MB

    if (ws_size < need) {
        size_t total = (size_t)NB * KOC * HWP;
        naive_kernel<<<(unsigned)((total + 255) / 256), 256, 0, stream>>>(x, W, b, out);
        return;
    }

    unsigned short* wt2 = (unsigned short*)d_ws;
    unsigned short* xt  = wt2 + wt_elems;        // 16B-aligned

    // prep zeroes only the 228 guard rows per slab (no full-buffer memset)
    prep_kernel<<<1152 + NB * 4 * 13 + 114, 256, 0, stream>>>(W, wt2, x, xt);
    gemm_kernel<<<1600, 256, 0, stream>>>(xt, wt2, b, out);
}